// Round 2
// baseline (235.206 us; speedup 1.0000x reference)
//
#include <hip/hip_runtime.h>

typedef short short8 __attribute__((ext_vector_type(8)));
typedef float floatx4 __attribute__((ext_vector_type(4)));
typedef float floatx16 __attribute__((ext_vector_type(16)));

#define DEV static __device__ __forceinline__

DEV unsigned short f2bf(float x) {
    union { float f; unsigned u; } v; v.f = x;
    unsigned r = v.u + 0x7FFFu + ((v.u >> 16) & 1u);
    return (unsigned short)(r >> 16);
}

DEV unsigned pk2(float lo, float hi) {
    return (unsigned)f2bf(lo) | ((unsigned)f2bf(hi) << 16);
}

// generic ptr -> LDS(as3) ptr: low 32 bits of flat LDS address are the LDS offset
DEV __attribute__((address_space(3))) unsigned int* lds_as3(void* p) {
    return (__attribute__((address_space(3))) unsigned int*)(unsigned int)(unsigned long long)p;
}
DEV const __attribute__((address_space(1))) unsigned int* gbl_as1(const void* p) {
    return (const __attribute__((address_space(1))) unsigned int*)(unsigned long long)p;
}

// ---------------------------------------------------------------------------
// f32 -> bf16 conversion of x (4096x1024), Wq/Wk/Wv (-> concat [3072][1024]), Wp
// 1,048,576 chunks of 8 elements.
__global__ __launch_bounds__(256) void cvt_all(
    const float* __restrict__ x,  const float* __restrict__ wq,
    const float* __restrict__ wk, const float* __restrict__ wv,
    const float* __restrict__ wp,
    unsigned short* __restrict__ xb, unsigned short* __restrict__ wqkv,
    unsigned short* __restrict__ wpb)
{
    long c = (long)blockIdx.x * 256 + threadIdx.x;
    const float* src; unsigned short* dst; long off;
    if      (c <  524288) { src = x;  dst = xb;             off = c;          }
    else if (c <  655360) { src = wq; dst = wqkv;           off = c - 524288; }
    else if (c <  786432) { src = wk; dst = wqkv + 1048576; off = c - 655360; }
    else if (c <  917504) { src = wv; dst = wqkv + 2097152; off = c - 786432; }
    else                  { src = wp; dst = wpb;            off = c - 917504; }
    float4 a = ((const float4*)src)[off * 2];
    float4 b = ((const float4*)src)[off * 2 + 1];
    ushort4 r0, r1;
    r0.x = f2bf(a.x); r0.y = f2bf(a.y); r0.z = f2bf(a.z); r0.w = f2bf(a.w);
    r1.x = f2bf(b.x); r1.y = f2bf(b.y); r1.z = f2bf(b.z); r1.w = f2bf(b.w);
    ((ushort4*)dst)[off * 2]     = r0;
    ((ushort4*)dst)[off * 2 + 1] = r1;
}

// ---------------------------------------------------------------------------
// NT GEMM: C[M,N] = A[M,K] * W[N,K]^T, bf16 in, f32 accum. m97 structure:
// 128x128 tile, BK=32, 256 threads = 4 waves (2x2), wave tile 64x64 = 4x4
// fragments of 16x16, mfma_f32_16x16x32_bf16, global_load_lds staging.
// EPI=0: scatter to Q[bh][s][64], K[bh][s][64], Vt[bh][64][s]  (N=3072)
// EPI=1: f32 out + bias                                        (N=1024)
template <int EPI>
__global__ __launch_bounds__(256) void gemm_bt(
    const unsigned short* __restrict__ A, const unsigned short* __restrict__ Bw,
    int M, int N, int K,
    unsigned short* __restrict__ Qd, unsigned short* __restrict__ Kd,
    unsigned short* __restrict__ Vtd,
    float* __restrict__ Cout, const float* __restrict__ bias)
{
    __shared__ unsigned short As[128 * 32];
    __shared__ unsigned short Bs[128 * 32];
    const int t    = threadIdx.x;
    const int lane = t & 63;
    const int wv   = t >> 6;
    const int wr   = (wv >> 1) * 64, wc = (wv & 1) * 64;
    const int lr   = lane & 15,      lg = lane >> 4;
    const int m0   = blockIdx.y * 128, n0 = blockIdx.x * 128;
    const int trow = t >> 2;          // staging row (0..63) per round
    const int tk   = (t & 3) * 8;     // staging k offset

    floatx4 acc[4][4];
#pragma unroll
    for (int i = 0; i < 4; ++i)
#pragma unroll
        for (int j = 0; j < 4; ++j)
#pragma unroll
            for (int r = 0; r < 4; ++r) acc[i][j][r] = 0.f;

    for (int k0 = 0; k0 < K; k0 += 32) {
        __syncthreads();
#pragma unroll
        for (int r = 0; r < 2; ++r) {
            const unsigned short* ga = A  + (size_t)(m0 + r * 64 + trow) * K + k0 + tk;
            const unsigned short* gb = Bw + (size_t)(n0 + r * 64 + trow) * K + k0 + tk;
            __builtin_amdgcn_global_load_lds(gbl_as1(ga), lds_as3(&As[(r * 256 + t) * 8]), 16, 0, 0);
            __builtin_amdgcn_global_load_lds(gbl_as1(gb), lds_as3(&Bs[(r * 256 + t) * 8]), 16, 0, 0);
        }
        __syncthreads();
        short8 af[4], bf[4];
#pragma unroll
        for (int i = 0; i < 4; ++i) {
            af[i] = *(const short8*)&As[(wr + i * 16 + lr) * 32 + lg * 8];
            bf[i] = *(const short8*)&Bs[(wc + i * 16 + lr) * 32 + lg * 8];
        }
#pragma unroll
        for (int i = 0; i < 4; ++i)
#pragma unroll
            for (int j = 0; j < 4; ++j)
                acc[i][j] = __builtin_amdgcn_mfma_f32_16x16x32_bf16(af[i], bf[j], acc[i][j], 0, 0, 0);
    }

    if (EPI == 1) {
#pragma unroll
        for (int j = 0; j < 4; ++j) {
            int n = n0 + wc + j * 16 + lr;
            float bv = bias[n];
#pragma unroll
            for (int i = 0; i < 4; ++i) {
                int mb = m0 + wr + i * 16 + lg * 4;
#pragma unroll
                for (int r = 0; r < 4; ++r)
                    Cout[(size_t)(mb + r) * N + n] = acc[i][j][r] + bv;
            }
        }
    } else {
        const int which = n0 >> 10;   // 0=Q 1=K 2=V (uniform per block; 128 | 1024)
#pragma unroll
        for (int j = 0; j < 4; ++j) {
            int n = n0 + wc + j * 16 + lr;
            int h = (n & 1023) >> 6, d = n & 63;
#pragma unroll
            for (int i = 0; i < 4; ++i) {
                int mb = m0 + wr + i * 16 + lg * 4;
                int b = mb >> 11, s0 = mb & 2047;
                size_t bh = (size_t)(b * 16 + h);
                if (which == 2) {
                    ushort4 pv;
                    pv.x = f2bf(acc[i][j][0]); pv.y = f2bf(acc[i][j][1]);
                    pv.z = f2bf(acc[i][j][2]); pv.w = f2bf(acc[i][j][3]);
                    *(ushort4*)&Vtd[(bh * 64 + d) * 2048 + s0] = pv;  // s0 % 4 == 0
                } else {
                    unsigned short* dst = (which ? Kd : Qd) + (bh * 2048 + s0) * 64 + d;
#pragma unroll
                    for (int r = 0; r < 4; ++r) dst[r * 64] = f2bf(acc[i][j][r]);
                }
            }
        }
    }
}

// ---------------------------------------------------------------------------
// Causal flash attention. Grid (32 bh, 16 qtiles), 256 threads = 4 waves.
// Wave w owns q rows [qt*128 + w*32, +32). KV tile = 32.
// Swapped QK^T: mfma(K,Q) -> lane owns q = lane&31 (col), kv in regs (rows).
// Swapped PV:   mfma(Vt,P) -> lane owns q (col), d in regs (rows).
// Operand layout (contiguous-8): m/n = lane&31, k = 8*(lane>>5)+e.
// D layout: col = lane&31, row = (reg&3)+8*(reg>>2)+4*(lane>>5).
__global__ __launch_bounds__(256) void attn_fwd(
    const unsigned short* __restrict__ Q, const unsigned short* __restrict__ Kg,
    const unsigned short* __restrict__ Vt, unsigned short* __restrict__ O)
{
    __shared__ unsigned short ot[4][32][80];   // per-wave transpose buffer (pad 80: 16B-aligned rows)
    const int bh = blockIdx.x;     // b*16+h
    const int qt = blockIdx.y;
    const int t  = threadIdx.x, w = t >> 6, l = t & 63;
    const int lq = l & 31, hh = l >> 5;
    const int qw = qt * 128 + w * 32;
    const unsigned short* Qp = Q  + (size_t)bh * 2048 * 64;
    const unsigned short* Kp = Kg + (size_t)bh * 2048 * 64;
    const unsigned short* Vp = Vt + (size_t)bh * 64 * 2048;

    short8 qf[4];
#pragma unroll
    for (int kk = 0; kk < 4; ++kk)
        qf[kk] = *(const short8*)&Qp[(qw + lq) * 64 + kk * 16 + hh * 8];

    floatx16 o0, o1;
#pragma unroll
    for (int r = 0; r < 16; ++r) { o0[r] = 0.f; o1[r] = 0.f; }
    float mrun = -1e30f, lrun = 0.f;

    for (int kv0 = 0; kv0 <= qw; kv0 += 32) {
        floatx16 sa;
#pragma unroll
        for (int r = 0; r < 16; ++r) sa[r] = 0.f;
#pragma unroll
        for (int kk = 0; kk < 4; ++kk) {
            short8 kf = *(const short8*)&Kp[(kv0 + lq) * 64 + kk * 16 + hh * 8];
            sa = __builtin_amdgcn_mfma_f32_32x32x16_bf16(kf, qf[kk], sa, 0, 0, 0);
        }
        float sv[16];
        float tm = -1e30f;
#pragma unroll
        for (int r = 0; r < 16; ++r) {
            int crow = (r & 3) + 8 * (r >> 2) + 4 * hh;   // kv row within tile
            float xx = sa[r] * 0.125f;                     // DK^-0.5
            if (kv0 + crow > qw + lq) xx = -1e30f;         // causal (only diag tile hits)
            sv[r] = xx;
            tm = fmaxf(tm, xx);
        }
        tm = fmaxf(tm, __shfl_xor(tm, 32));
        float mn = fmaxf(mrun, tm);
        float f  = __expf(mrun - mn);
        float ps = 0.f;
#pragma unroll
        for (int r = 0; r < 16; ++r) { sv[r] = __expf(sv[r] - mn); ps += sv[r]; }
        ps += __shfl_xor(ps, 32);
        lrun = lrun * f + ps;
        mrun = mn;
#pragma unroll
        for (int r = 0; r < 16; ++r) { o0[r] *= f; o1[r] *= f; }

#pragma unroll
        for (int c = 0; c < 2; ++c) {   // kv chunks of 16
            unsigned a0 = pk2(sv[c*8+0], sv[c*8+1]);   // own kv {4hh,4hh+1}+16c
            unsigned a1 = pk2(sv[c*8+2], sv[c*8+3]);   // {4hh+2,4hh+3}
            unsigned b0 = pk2(sv[c*8+4], sv[c*8+5]);   // {8+4hh,9+4hh}
            unsigned b1 = pk2(sv[c*8+6], sv[c*8+7]);   // {10+4hh,11+4hh}
            unsigned sa0 = __shfl_xor(a0, 32), sa1 = __shfl_xor(a1, 32);
            unsigned sb0 = __shfl_xor(b0, 32), sb1 = __shfl_xor(b1, 32);
            union { unsigned u[4]; short8 v; } pf;
            pf.u[0] = hh ? sb0 : a0;   // kv {0,1} / {8,9}
            pf.u[1] = hh ? sb1 : a1;   // kv {2,3} / {10,11}
            pf.u[2] = hh ? b0  : sa0;  // kv {4,5} / {12,13}
            pf.u[3] = hh ? b1  : sa1;  // kv {6,7} / {14,15}
            short8 vf0 = *(const short8*)&Vp[(size_t)(lq)      * 2048 + kv0 + c * 16 + hh * 8];
            short8 vf1 = *(const short8*)&Vp[(size_t)(32 + lq) * 2048 + kv0 + c * 16 + hh * 8];
            o0 = __builtin_amdgcn_mfma_f32_32x32x16_bf16(vf0, pf.v, o0, 0, 0, 0);
            o1 = __builtin_amdgcn_mfma_f32_32x32x16_bf16(vf1, pf.v, o1, 0, 0, 0);
        }
    }

    float inv = 1.f / lrun;
#pragma unroll
    for (int r = 0; r < 16; ++r) {
        int crow = (r & 3) + 8 * (r >> 2) + 4 * hh;
        ot[w][lq][crow]      = f2bf(o0[r] * inv);
        ot[w][lq][32 + crow] = f2bf(o1[r] * inv);
    }
    asm volatile("s_waitcnt lgkmcnt(0)" ::: "memory");   // intra-wave LDS transpose
    const int b = bh >> 4, h = bh & 15;
    const int row = l >> 1, part = l & 1;
    size_t obase = (size_t)(b * 2048 + qt * 128 + w * 32 + row) * 1024 + h * 64 + part * 32;
#pragma unroll
    for (int jj = 0; jj < 4; ++jj) {
        uint4 v = *(const uint4*)&ot[w][row][part * 32 + jj * 8];
        *(uint4*)&O[obase + jj * 8] = v;
    }
}

// ---------------------------------------------------------------------------
extern "C" void kernel_launch(void* const* d_in, const int* in_sizes, int n_in,
                              void* d_out, int out_size, void* d_ws, size_t ws_size,
                              hipStream_t stream)
{
    const float* x  = (const float*)d_in[0];
    const float* Wq = (const float*)d_in[1];
    const float* Wk = (const float*)d_in[2];
    const float* Wv = (const float*)d_in[3];
    const float* Wp = (const float*)d_in[4];
    const float* bp = (const float*)d_in[5];
    float* out = (float*)d_out;

    char* ws = (char*)d_ws;
    unsigned short* xb   = (unsigned short*)(ws);              //  8.0 MiB  x bf16
    unsigned short* wqkv = (unsigned short*)(ws + 8388608);    //  6.0 MiB  [3072][1024]
    unsigned short* wpb  = (unsigned short*)(ws + 14680064);   //  2.0 MiB
    unsigned short* Qw   = (unsigned short*)(ws + 16777216);   //  [bh][s][64]
    unsigned short* Kw   = (unsigned short*)(ws + 25165824);   //  [bh][s][64]
    unsigned short* Vtw  = (unsigned short*)(ws + 33554432);   //  [bh][64][s]
    unsigned short* Ow   = (unsigned short*)(ws + 41943040);   //  [4096][1024]

    cvt_all<<<4096, 256, 0, stream>>>(x, Wq, Wk, Wv, Wp, xb, wqkv, wpb);
    gemm_bt<0><<<dim3(24, 32), 256, 0, stream>>>(xb, wqkv, 4096, 3072, 1024,
                                                 Qw, Kw, Vtw, nullptr, nullptr);
    attn_fwd<<<dim3(32, 16), 256, 0, stream>>>(Qw, Kw, Vtw, Ow);
    gemm_bt<1><<<dim3(8, 32), 256, 0, stream>>>(Ow, wpb, 4096, 1024, 1024,
                                                nullptr, nullptr, nullptr, out, bp);
}

// Round 5
// 234.948 us; speedup vs baseline: 1.0011x; 1.0011x over previous
//
#include <hip/hip_runtime.h>
#include <hip/hip_bf16.h>

typedef short short8 __attribute__((ext_vector_type(8)));
typedef float floatx4 __attribute__((ext_vector_type(4)));
typedef float floatx16 __attribute__((ext_vector_type(16)));

#define DEV static __device__ __forceinline__

DEV unsigned short f2bf(float x) {
    union { float f; unsigned u; } v; v.f = x;
    unsigned r = v.u + 0x7FFFu + ((v.u >> 16) & 1u);
    return (unsigned short)(r >> 16);
}

// packed f32x2 -> bf16x2 via HIP intrinsic (compiler emits v_cvt_pk_bf16_f32)
DEV unsigned pk2(float lo, float hi) {
    union { __hip_bfloat162 h; unsigned u; } v;
    v.h = __float22bfloat162_rn(make_float2(lo, hi));
    return v.u;
}

DEV float fexp2(float x) {
#if __has_builtin(__builtin_amdgcn_exp2f)
    return __builtin_amdgcn_exp2f(x);
#else
    return exp2f(x);
#endif
}

// generic ptr -> LDS(as3) ptr: low 32 bits of flat LDS address are the LDS offset
DEV __attribute__((address_space(3))) unsigned int* lds_as3(void* p) {
    return (__attribute__((address_space(3))) unsigned int*)(unsigned int)(unsigned long long)p;
}
DEV const __attribute__((address_space(1))) unsigned int* gbl_as1(const void* p) {
    return (const __attribute__((address_space(1))) unsigned int*)(unsigned long long)p;
}

// ---------------------------------------------------------------------------
// f32 -> bf16 conversion of x (4096x1024), Wq/Wk/Wv (-> concat [3072][1024]), Wp
__global__ __launch_bounds__(256) void cvt_all(
    const float* __restrict__ x,  const float* __restrict__ wq,
    const float* __restrict__ wk, const float* __restrict__ wv,
    const float* __restrict__ wp,
    unsigned short* __restrict__ xb, unsigned short* __restrict__ wqkv,
    unsigned short* __restrict__ wpb)
{
    long c = (long)blockIdx.x * 256 + threadIdx.x;
    const float* src; unsigned short* dst; long off;
    if      (c <  524288) { src = x;  dst = xb;             off = c;          }
    else if (c <  655360) { src = wq; dst = wqkv;           off = c - 524288; }
    else if (c <  786432) { src = wk; dst = wqkv + 1048576; off = c - 655360; }
    else if (c <  917504) { src = wv; dst = wqkv + 2097152; off = c - 786432; }
    else                  { src = wp; dst = wpb;            off = c - 917504; }
    float4 a = ((const float4*)src)[off * 2];
    float4 b = ((const float4*)src)[off * 2 + 1];
    ushort4 r0, r1;
    r0.x = f2bf(a.x); r0.y = f2bf(a.y); r0.z = f2bf(a.z); r0.w = f2bf(a.w);
    r1.x = f2bf(b.x); r1.y = f2bf(b.y); r1.z = f2bf(b.z); r1.w = f2bf(b.w);
    ((ushort4*)dst)[off * 2]     = r0;
    ((ushort4*)dst)[off * 2 + 1] = r1;
}

// ---------------------------------------------------------------------------
// NT GEMM (m97 structure, validated round 2 incl. post-timing)
template <int EPI>
__global__ __launch_bounds__(256) void gemm_bt(
    const unsigned short* __restrict__ A, const unsigned short* __restrict__ Bw,
    int M, int N, int K,
    unsigned short* __restrict__ Qd, unsigned short* __restrict__ Kd,
    unsigned short* __restrict__ Vtd,
    float* __restrict__ Cout, const float* __restrict__ bias)
{
    __shared__ unsigned short As[128 * 32];
    __shared__ unsigned short Bs[128 * 32];
    const int t    = threadIdx.x;
    const int lane = t & 63;
    const int wv   = t >> 6;
    const int wr   = (wv >> 1) * 64, wc = (wv & 1) * 64;
    const int lr   = lane & 15,      lg = lane >> 4;
    const int m0   = blockIdx.y * 128, n0 = blockIdx.x * 128;
    const int trow = t >> 2;
    const int tk   = (t & 3) * 8;

    floatx4 acc[4][4];
#pragma unroll
    for (int i = 0; i < 4; ++i)
#pragma unroll
        for (int j = 0; j < 4; ++j)
#pragma unroll
            for (int r = 0; r < 4; ++r) acc[i][j][r] = 0.f;

    for (int k0 = 0; k0 < K; k0 += 32) {
        __syncthreads();
#pragma unroll
        for (int r = 0; r < 2; ++r) {
            const unsigned short* ga = A  + (size_t)(m0 + r * 64 + trow) * K + k0 + tk;
            const unsigned short* gb = Bw + (size_t)(n0 + r * 64 + trow) * K + k0 + tk;
            __builtin_amdgcn_global_load_lds(gbl_as1(ga), lds_as3(&As[(r * 256 + t) * 8]), 16, 0, 0);
            __builtin_amdgcn_global_load_lds(gbl_as1(gb), lds_as3(&Bs[(r * 256 + t) * 8]), 16, 0, 0);
        }
        __syncthreads();
        short8 af[4], bf[4];
#pragma unroll
        for (int i = 0; i < 4; ++i) {
            af[i] = *(const short8*)&As[(wr + i * 16 + lr) * 32 + lg * 8];
            bf[i] = *(const short8*)&Bs[(wc + i * 16 + lr) * 32 + lg * 8];
        }
#pragma unroll
        for (int i = 0; i < 4; ++i)
#pragma unroll
            for (int j = 0; j < 4; ++j)
                acc[i][j] = __builtin_amdgcn_mfma_f32_16x16x32_bf16(af[i], bf[j], acc[i][j], 0, 0, 0);
    }

    if (EPI == 1) {
#pragma unroll
        for (int j = 0; j < 4; ++j) {
            int n = n0 + wc + j * 16 + lr;
            float bv = bias[n];
#pragma unroll
            for (int i = 0; i < 4; ++i) {
                int mb = m0 + wr + i * 16 + lg * 4;
#pragma unroll
                for (int r = 0; r < 4; ++r)
                    Cout[(size_t)(mb + r) * N + n] = acc[i][j][r] + bv;
            }
        }
    } else {
        const int which = n0 >> 10;   // 0=Q 1=K 2=V
#pragma unroll
        for (int j = 0; j < 4; ++j) {
            int n = n0 + wc + j * 16 + lr;
            int h = (n & 1023) >> 6, d = n & 63;
#pragma unroll
            for (int i = 0; i < 4; ++i) {
                int mb = m0 + wr + i * 16 + lg * 4;
                int b = mb >> 11, s0 = mb & 2047;
                size_t bh = (size_t)(b * 16 + h);
                if (which == 2) {
                    ushort4 pv;
                    pv.x = f2bf(acc[i][j][0]); pv.y = f2bf(acc[i][j][1]);
                    pv.z = f2bf(acc[i][j][2]); pv.w = f2bf(acc[i][j][3]);
                    *(ushort4*)&Vtd[(bh * 64 + d) * 2048 + s0] = pv;
                } else {
                    unsigned short* dst = (which ? Kd : Qd) + (bh * 2048 + s0) * 64 + d;
#pragma unroll
                    for (int r = 0; r < 4; ++r) dst[r * 64] = f2bf(acc[i][j][r]);
                }
            }
        }
    }
}

// ---------------------------------------------------------------------------
// Causal flash attention — round-2 validated structure (intra-wave only, no
// cross-wave communication), with wave-local improvements:
//   * heavy-first dispatch (qt = 15 - blockIdx.y): removes the straggler tail
//   * log2-domain softmax (SCALE2 = DK^-0.5*log2e folded into the S scale)
//   * diag-only causal masking (wave-uniform kv0==qw branch)
//   * T13 defer-max (skip O-rescale when max growth <= 8 in log2 domain)
//   * pk2 via v_cvt_pk_bf16_f32
// Grid (32 bh, 16 qt), 256 threads = 4 waves; wave w owns q rows qt*128+w*32.
// Swapped QK^T: mfma(K,Q) -> lane owns q = lane&31 (col), kv in regs (rows).
// Swapped PV:   mfma(Vt,P) -> lane owns q (col), d in regs (rows).
// D layout: col = lane&31, row = (reg&3)+8*(reg>>2)+4*(lane>>5).
__global__ __launch_bounds__(256) void attn_fwd(
    const unsigned short* __restrict__ Q, const unsigned short* __restrict__ Kg,
    const unsigned short* __restrict__ Vt, unsigned short* __restrict__ O)
{
    __shared__ unsigned short ot[4][32][80];   // per-wave transpose buffer (16B-aligned rows)
    const int bh = blockIdx.x;                 // b*16+h
    const int qt = 15 - blockIdx.y;            // heavy-first
    const int t  = threadIdx.x, w = t >> 6, l = t & 63;
    const int lq = l & 31, hh = l >> 5;
    const int qw = qt * 128 + w * 32;
    const unsigned short* Qp = Q  + (size_t)bh * 2048 * 64;
    const unsigned short* Kp = Kg + (size_t)bh * 2048 * 64;
    const unsigned short* Vp = Vt + (size_t)bh * 64 * 2048;

    const float SCALE2 = 0.18033688011112042f; // DK^-0.5 * log2(e)

    short8 qf[4];
#pragma unroll
    for (int kk = 0; kk < 4; ++kk)
        qf[kk] = *(const short8*)&Qp[(qw + lq) * 64 + kk * 16 + hh * 8];

    floatx16 o0, o1;
#pragma unroll
    for (int r = 0; r < 16; ++r) { o0[r] = 0.f; o1[r] = 0.f; }
    float mrun = -1e30f, lrun = 0.f;

    for (int kv0 = 0; kv0 <= qw; kv0 += 32) {
        floatx16 sa;
#pragma unroll
        for (int r = 0; r < 16; ++r) sa[r] = 0.f;
#pragma unroll
        for (int kk = 0; kk < 4; ++kk) {
            short8 kf = *(const short8*)&Kp[(kv0 + lq) * 64 + kk * 16 + hh * 8];
            sa = __builtin_amdgcn_mfma_f32_32x32x16_bf16(kf, qf[kk], sa, 0, 0, 0);
        }
        float sv[16];
        float tm = -1e30f;
        if (kv0 == qw) {           // diagonal tile: causal mask (wave-uniform branch)
#pragma unroll
            for (int r = 0; r < 16; ++r) {
                int crow = (r & 3) + 8 * (r >> 2) + 4 * hh;
                float xx = sa[r] * SCALE2;
                if (crow > lq) xx = -1e30f;
                sv[r] = xx;
                tm = fmaxf(tm, xx);
            }
        } else {
#pragma unroll
            for (int r = 0; r < 16; ++r) {
                float xx = sa[r] * SCALE2;
                sv[r] = xx;
                tm = fmaxf(tm, xx);
            }
        }
        tm = fmaxf(tm, __shfl_xor(tm, 32));
        if (!__all(tm - mrun <= 8.f)) {        // T13 defer-max (log2 domain)
            float mn = fmaxf(mrun, tm);
            float f  = fexp2(mrun - mn);
            lrun *= f;
#pragma unroll
            for (int r = 0; r < 16; ++r) { o0[r] *= f; o1[r] *= f; }
            mrun = mn;
        }
        float ps = 0.f;
#pragma unroll
        for (int r = 0; r < 16; ++r) { sv[r] = fexp2(sv[r] - mrun); ps += sv[r]; }
        ps += __shfl_xor(ps, 32);
        lrun += ps;

#pragma unroll
        for (int c = 0; c < 2; ++c) {   // kv chunks of 16
            unsigned a0 = pk2(sv[c*8+0], sv[c*8+1]);
            unsigned a1 = pk2(sv[c*8+2], sv[c*8+3]);
            unsigned b0 = pk2(sv[c*8+4], sv[c*8+5]);
            unsigned b1 = pk2(sv[c*8+6], sv[c*8+7]);
            unsigned sa0 = __shfl_xor(a0, 32), sa1 = __shfl_xor(a1, 32);
            unsigned sb0 = __shfl_xor(b0, 32), sb1 = __shfl_xor(b1, 32);
            union { unsigned u[4]; short8 v; } pf;
            pf.u[0] = hh ? sb0 : a0;
            pf.u[1] = hh ? sb1 : a1;
            pf.u[2] = hh ? b0  : sa0;
            pf.u[3] = hh ? b1  : sa1;
            short8 vf0 = *(const short8*)&Vp[(size_t)(lq)      * 2048 + kv0 + c * 16 + hh * 8];
            short8 vf1 = *(const short8*)&Vp[(size_t)(32 + lq) * 2048 + kv0 + c * 16 + hh * 8];
            o0 = __builtin_amdgcn_mfma_f32_32x32x16_bf16(vf0, pf.v, o0, 0, 0, 0);
            o1 = __builtin_amdgcn_mfma_f32_32x32x16_bf16(vf1, pf.v, o1, 0, 0, 0);
        }
    }

    float inv = 1.f / lrun;
#pragma unroll
    for (int r = 0; r < 16; ++r) {
        int crow = (r & 3) + 8 * (r >> 2) + 4 * hh;
        ot[w][lq][crow]      = f2bf(o0[r] * inv);
        ot[w][lq][32 + crow] = f2bf(o1[r] * inv);
    }
    asm volatile("s_waitcnt lgkmcnt(0)" ::: "memory");   // intra-wave LDS transpose
    const int b = bh >> 4, h = bh & 15;
    const int row = l >> 1, part = l & 1;
    size_t obase = (size_t)(b * 2048 + qt * 128 + w * 32 + row) * 1024 + h * 64 + part * 32;
#pragma unroll
    for (int jj = 0; jj < 4; ++jj) {
        uint4 v = *(const uint4*)&ot[w][row][part * 32 + jj * 8];
        *(uint4*)&O[obase + jj * 8] = v;
    }
}

// ---------------------------------------------------------------------------
extern "C" void kernel_launch(void* const* d_in, const int* in_sizes, int n_in,
                              void* d_out, int out_size, void* d_ws, size_t ws_size,
                              hipStream_t stream)
{
    const float* x  = (const float*)d_in[0];
    const float* Wq = (const float*)d_in[1];
    const float* Wk = (const float*)d_in[2];
    const float* Wv = (const float*)d_in[3];
    const float* Wp = (const float*)d_in[4];
    const float* bp = (const float*)d_in[5];
    float* out = (float*)d_out;

    char* ws = (char*)d_ws;
    unsigned short* xb   = (unsigned short*)(ws);              //  8.0 MiB  x bf16
    unsigned short* wqkv = (unsigned short*)(ws + 8388608);    //  6.0 MiB  [3072][1024]
    unsigned short* wpb  = (unsigned short*)(ws + 14680064);   //  2.0 MiB
    unsigned short* Qw   = (unsigned short*)(ws + 16777216);   //  [bh][s][64]
    unsigned short* Kw   = (unsigned short*)(ws + 25165824);   //  [bh][s][64]
    unsigned short* Vtw  = (unsigned short*)(ws + 33554432);   //  [bh][64][s]
    unsigned short* Ow   = (unsigned short*)(ws + 41943040);   //  [4096][1024]

    cvt_all<<<4096, 256, 0, stream>>>(x, Wq, Wk, Wv, Wp, xb, wqkv, wpb);
    gemm_bt<0><<<dim3(24, 32), 256, 0, stream>>>(xb, wqkv, 4096, 3072, 1024,
                                                 Qw, Kw, Vtw, nullptr, nullptr);
    attn_fwd<<<dim3(32, 16), 256, 0, stream>>>(Qw, Kw, Vtw, Ow);
    gemm_bt<1><<<dim3(8, 32), 256, 0, stream>>>(Ow, wpb, 4096, 1024, 1024,
                                                nullptr, nullptr, nullptr, out, bp);
}